// Round 7
// baseline (101.242 us; speedup 1.0000x reference)
//
#include <hip/hip_runtime.h>
#include <math.h>

#define N_SEQ 2048
#define DIMC 512
#define INNER 256
#define C2F (0.17677669529663687f * 1.4426950408889634f)  // scale * log2(e)
#define C2F2 (C2F * C2F)

typedef short bf16x8 __attribute__((ext_vector_type(8)));
typedef float f32x4 __attribute__((ext_vector_type(4)));

// ws layout (bytes):
//  0..4MB     : Q bf16 [bh][g:4][n][8]; combine later overwrites with att16 [b][n][256]
//  2..4MB     : (K overlaps att16 upper half -- K dead before combine writes)
//  4..6MB     : Vt bf16 [bh][c:256][d:32][8]
//  12..12.25  : q2*C2F^2   12.25..12.5 : k2*C2F^2   12.5..13 : lpart [jh][bh][q]
//  13..29MB   : Opart fp32 [jh][bh][q][d:32]  (overwrites dead xt16)
//  21..29MB   : xt16 (dead after qkv_mfma)    29..29.75MB : wq16
//  17..17.25MB region unused now; wo16 @ 30MB..30.25MB

static __device__ __forceinline__ ushort f2bf(float f) {
    uint x = __float_as_uint(f);
    x += 0x7fff + ((x >> 16) & 1);
    return (ushort)(x >> 16);
}
static __device__ __forceinline__ float bf2f(ushort u) {
    return __uint_as_float(((uint)u) << 16);
}
static __device__ __forceinline__ float fast_exp2_neg(float x) {  // exp2(-x)
    float r; asm("v_exp_f32 %0, -%1" : "=v"(r) : "v"(x)); return r;
}
static __device__ __forceinline__ float fast_sqrt(float x) {
    float r; asm("v_sqrt_f32 %0, %1" : "=v"(r) : "v"(x)); return r;
}

// ---------------------------------------------------------------------------
// x [b][c][n] f32 -> xt [b][n][c] bf16
// ---------------------------------------------------------------------------
__global__ void xpose_cvt(const float* __restrict__ x, ushort* __restrict__ xt) {
    __shared__ __align__(16) ushort T[64][72];
    const int b = blockIdx.z;
    const int c0 = blockIdx.y * 64;
    const int n0 = blockIdx.x * 64;
    const int t = threadIdx.x;
    const int cl = t >> 4;
    const int n4 = (t & 15) * 4;
    const float* xb = x + ((size_t)b * DIMC + c0) * N_SEQ + n0;
#pragma unroll
    for (int cc = 0; cc < 4; ++cc) {
        const int c = cl + cc * 16;
        float4 v = *(const float4*)(xb + (size_t)c * N_SEQ + n4);
        T[n4 + 0][c] = f2bf(v.x);
        T[n4 + 1][c] = f2bf(v.y);
        T[n4 + 2][c] = f2bf(v.z);
        T[n4 + 3][c] = f2bf(v.w);
    }
    __syncthreads();
    const int nl = t >> 2;
    const int c16 = (t & 3) * 16;
    uint4 v0 = *(const uint4*)&T[nl][c16];
    uint4 v1 = *(const uint4*)&T[nl][c16 + 8];
    ushort* dst = xt + ((size_t)b * N_SEQ + n0 + nl) * DIMC + c0 + c16;
    *(uint4*)dst = v0;
    *(uint4*)(dst + 8) = v1;
}

// both weight conversions in one launch
__global__ void wcvt2(const float* __restrict__ wq, const float* __restrict__ wo,
                      ushort* __restrict__ wq16, ushort* __restrict__ wo16) {
    const int bid = blockIdx.x;
    if (bid < 384) {
        int i = (bid * 256 + threadIdx.x) * 4;
        float4 v = *(const float4*)(wq + i);
        ushort4 p;
        p.x = f2bf(v.x); p.y = f2bf(v.y); p.z = f2bf(v.z); p.w = f2bf(v.w);
        *(ushort4*)(wq16 + i) = p;
    } else {
        int i = ((bid - 384) * 256 + threadIdx.x) * 4;
        float4 v = *(const float4*)(wo + i);
        ushort4 p;
        p.x = f2bf(v.x); p.y = f2bf(v.y); p.z = f2bf(v.z); p.w = f2bf(v.w);
        *(ushort4*)(wo16 + i) = p;
    }
}

// ---------------------------------------------------------------------------
// QKV projection, bf16 MFMA. 64x64 tile, BK=32, 4 waves.
// ---------------------------------------------------------------------------
__global__ __launch_bounds__(256) void qkv_mfma(const ushort* __restrict__ xt,
        const ushort* __restrict__ w16, ushort* __restrict__ ws16) {
    __shared__ __align__(16) ushort Wls[4 * 520];
    __shared__ __align__(16) ushort Xls[4 * 520];
    const int b = blockIdx.z;
    const int o0 = blockIdx.y * 64;
    const int n0 = blockIdx.x * 64;
    const int t = threadIdx.x;
    const int l = t & 63, w = t >> 6;
    const int q15 = l & 15, g = l >> 4;
    f32x4 acc[4];
#pragma unroll
    for (int nn = 0; nn < 4; ++nn) acc[nn] = (f32x4){0.f, 0.f, 0.f, 0.f};
    const int srow = t >> 2, sg = t & 3;
    const ushort* wsrc = w16 + (size_t)(o0 + srow) * DIMC + sg * 8;
    const ushort* xsrc = xt + ((size_t)b * N_SEQ + n0 + srow) * DIMC + sg * 8;
    uint4 wreg = *(const uint4*)wsrc;
    uint4 xreg = *(const uint4*)xsrc;
    for (int k0 = 0; k0 < DIMC; k0 += 32) {
        __builtin_amdgcn_s_barrier();
        __builtin_amdgcn_sched_barrier(0);
        *(uint4*)(Wls + sg * 520 + srow * 8) = wreg;
        *(uint4*)(Xls + sg * 520 + srow * 8) = xreg;
        if (k0 + 32 < DIMC) {
            wreg = *(const uint4*)(wsrc + k0 + 32);
            xreg = *(const uint4*)(xsrc + k0 + 32);
        }
        asm volatile("s_waitcnt lgkmcnt(0)" ::: "memory");
        __builtin_amdgcn_s_barrier();
        __builtin_amdgcn_sched_barrier(0);
        bf16x8 af = *(const bf16x8*)(Wls + g * 520 + (16 * w + q15) * 8);
        __builtin_amdgcn_s_setprio(1);
#pragma unroll
        for (int nn = 0; nn < 4; ++nn) {
            bf16x8 bfr = *(const bf16x8*)(Xls + g * 520 + (16 * nn + q15) * 8);
            acc[nn] = __builtin_amdgcn_mfma_f32_16x16x32_bf16(af, bfr, acc[nn], 0, 0, 0);
        }
        __builtin_amdgcn_s_setprio(0);
    }
    const int oatom = o0 + 16 * w;
    const int t_idx = oatom >> 8;
    const int h = (oatom >> 5) & 7;
    const int bh = b * 8 + h;
    const int d0 = (oatom & 31) + 4 * g;
    if (t_idx < 2) {
        ushort* dst = ws16 + (size_t)t_idx * 2097152 + (size_t)bh * 65536
                      + (size_t)(d0 >> 3) * 16384 + (d0 & 7);
#pragma unroll
        for (int nn = 0; nn < 4; ++nn) {
            const int n_ = n0 + 16 * nn + q15;
            ushort4 p;
            p.x = f2bf(acc[nn][0]); p.y = f2bf(acc[nn][1]);
            p.z = f2bf(acc[nn][2]); p.w = f2bf(acc[nn][3]);
            *(ushort4*)(dst + (size_t)n_ * 8) = p;
        }
    } else {
        ushort* dst = ws16 + (size_t)4194304 + (size_t)bh * 65536;
#pragma unroll
        for (int nn = 0; nn < 4; ++nn) {
            const int n_ = n0 + 16 * nn + q15;
            ushort* dd = dst + (size_t)(n_ >> 3) * 256 + (n_ & 7);
            dd[(d0 + 0) * 8] = f2bf(acc[nn][0]);
            dd[(d0 + 1) * 8] = f2bf(acc[nn][1]);
            dd[(d0 + 2) * 8] = f2bf(acc[nn][2]);
            dd[(d0 + 3) * 8] = f2bf(acc[nn][3]);
        }
    }
}

// ---------------------------------------------------------------------------
// q2/k2 from bf16 values, prescaled by C2F^2
// ---------------------------------------------------------------------------
__global__ void sq_kernel(const ushort* __restrict__ ws16, float* __restrict__ q2,
                          float* __restrict__ k2) {
    const int which = blockIdx.y;
    const int idx = blockIdx.x * 256 + threadIdx.x;
    const int bh = idx >> 11, n = idx & 2047;
    const ushort* base = ws16 + (size_t)which * 2097152 + (size_t)bh * 65536
                         + (size_t)n * 8;
    float s = 0.f;
#pragma unroll
    for (int g = 0; g < 4; ++g) {
        uint4 v = *(const uint4*)(base + (size_t)g * 16384);
        uint a[4] = {v.x, v.y, v.z, v.w};
#pragma unroll
        for (int e = 0; e < 4; ++e) {
            float lo = bf2f((ushort)(a[e] & 0xffff));
            float hi = bf2f((ushort)(a[e] >> 16));
            s += lo * lo + hi * hi;
        }
    }
    (which == 0 ? q2 : k2)[idx] = s * (float)C2F2;
}

// ---------------------------------------------------------------------------
// Flash L2 attention, j-split x2 for occupancy (latency hiding). m=0 fixed
// shift (exact by shift-invariance); partials combine by pure addition.
// Each block: 64 q-rows x 1024 j. Writes unnormalized O (fp32) + l partial.
// ---------------------------------------------------------------------------
__global__ __launch_bounds__(256) void attn_partial(
        const ushort* __restrict__ ws16, const float* __restrict__ q2g,
        const float* __restrict__ k2g, float* __restrict__ Opart,
        float* __restrict__ lpart) {
    __shared__ __align__(16) ushort Pls[4][16][140];
    const int bid = blockIdx.x;                    // 2048 blocks
    const int sw = (bid & 7) * 256 + (bid >> 3);   // XCD swizzle: 4 bh per XCD
    const int jh = sw & 1;
    const int q0 = ((sw >> 1) & 31) * 64;
    const int bh = sw >> 6;
    const int tid = threadIdx.x;
    const int l = tid & 63;
    const int w = tid >> 6;
    const int q15 = l & 15;
    const int g = l >> 4;
    const int qrow = q0 + 16 * w + q15;

    const ushort* Qbh = ws16 + (size_t)bh * 65536;
    const ushort* Kbh = ws16 + 2097152 + (size_t)bh * 65536;
    const ushort* Vbh = ws16 + 4194304 + (size_t)bh * 65536;
    const float* k2bh = k2g + (size_t)bh * 2048;

    const bf16x8 qf = *(const bf16x8*)(Qbh + (size_t)g * 16384 + (size_t)qrow * 8);
    const float q2v = q2g[(size_t)bh * 2048 + qrow];

    f32x4 accO[2];
    accO[0] = (f32x4){0.f, 0.f, 0.f, 0.f};
    accO[1] = (f32x4){0.f, 0.f, 0.f, 0.f};
    float lsm = 0.f;

    for (int t = 0; t < 8; ++t) {
        const int j0 = jh * 1024 + t * 128;
        bf16x8 kf[8], vfr[8];
        float4 kk[8];
#pragma unroll
        for (int k = 0; k < 8; ++k)
            kf[k] = *(const bf16x8*)(Kbh + (size_t)g * 16384
                                     + (size_t)(j0 + 16 * k + q15) * 8);
#pragma unroll
        for (int jc = 0; jc < 4; ++jc)
#pragma unroll
            for (int d = 0; d < 2; ++d)
                vfr[jc * 2 + d] = *(const bf16x8*)(Vbh + (size_t)j0 * 32
                                   + (size_t)(4 * jc + g) * 256
                                   + (size_t)(16 * d + q15) * 8);
#pragma unroll
        for (int k = 0; k < 8; ++k)
            kk[k] = *(const float4*)(k2bh + j0 + 16 * k + 4 * g);

        const f32x4 zz = (f32x4){0.f, 0.f, 0.f, 0.f};
        f32x4 st[8];
        __builtin_amdgcn_s_setprio(1);
#pragma unroll
        for (int k = 0; k < 8; ++k)
            st[k] = __builtin_amdgcn_mfma_f32_16x16x32_bf16(kf[k], qf, zz, 0, 0, 0);
        __builtin_amdgcn_s_setprio(0);

        // scores: d2s = (q2+k2-2qk)*C2F^2 via prescale; p = exp2(-sqrt(d2s))
        float lt = 0.f;
#pragma unroll
        for (int k = 0; k < 8; ++k) {
            float ka[4] = {kk[k].x, kk[k].y, kk[k].z, kk[k].w};
            float p[4];
#pragma unroll
            for (int r = 0; r < 4; ++r) {
                float a = q2v + ka[r];
                float d2 = fmaf(-2.f * (float)C2F2, st[k][r], a);
                p[r] = fast_exp2_neg(fast_sqrt(fmaxf(d2, 1e-12f)));
            }
            lt += (p[0] + p[1]) + (p[2] + p[3]);
            uint pk0, pk1;
            asm("v_cvt_pk_bf16_f32 %0, %1, %2" : "=v"(pk0) : "v"(p[0]), "v"(p[1]));
            asm("v_cvt_pk_bf16_f32 %0, %1, %2" : "=v"(pk1) : "v"(p[2]), "v"(p[3]));
            uint2 pv; pv.x = pk0; pv.y = pk1;
            *(uint2*)&Pls[w][q15][16 * k + 4 * g] = pv;
        }
        lsm += lt;

        __builtin_amdgcn_s_setprio(1);
#pragma unroll
        for (int jc = 0; jc < 4; ++jc) {
            bf16x8 pf = *(const bf16x8*)&Pls[w][q15][32 * jc + 8 * g];
#pragma unroll
            for (int d = 0; d < 2; ++d)
                accO[d] = __builtin_amdgcn_mfma_f32_16x16x32_bf16(vfr[jc * 2 + d],
                                                                  pf, accO[d], 0, 0, 0);
        }
        __builtin_amdgcn_s_setprio(0);
    }

    lsm += __shfl_xor(lsm, 16);
    lsm += __shfl_xor(lsm, 32);
    float* orow = Opart + (((size_t)jh * 32 + bh) * 2048 + qrow) * 32 + 4 * g;
#pragma unroll
    for (int d = 0; d < 2; ++d) {
        float4 o;
        o.x = accO[d][0]; o.y = accO[d][1]; o.z = accO[d][2]; o.w = accO[d][3];
        *(float4*)(orow + 16 * d) = o;
    }
    if (g == 0)
        lpart[(size_t)jh * 65536 + (size_t)bh * 2048 + qrow] = lsm;
}

// ---------------------------------------------------------------------------
// combine halves + normalize + bf16 att [b][n][256]
// ---------------------------------------------------------------------------
__global__ void combine_norm(const float* __restrict__ Opart,
                             const float* __restrict__ lpart,
                             ushort* __restrict__ att16) {
    const int R = blockIdx.x * 32 + (threadIdx.x >> 3);   // bh*2048 + n
    const int d0 = (threadIdx.x & 7) * 4;
    float4 a = *(const float4*)(Opart + (size_t)R * 32 + d0);
    float4 b = *(const float4*)(Opart + (size_t)2097152 + (size_t)R * 32 + d0);
    const float inv = 1.f / (lpart[R] + lpart[R + 65536]);
    ushort4 o;
    o.x = f2bf((a.x + b.x) * inv); o.y = f2bf((a.y + b.y) * inv);
    o.z = f2bf((a.z + b.z) * inv); o.w = f2bf((a.w + b.w) * inv);
    const int bh = R >> 11, n = R & 2047;
    att16[0] = att16[0];  // no-op guard against DCE paranoia (kept trivial)
    *(ushort4*)(att16 + (((size_t)(bh >> 3) * N_SEQ + n) * INNER
                         + (bh & 7) * 32 + d0)) = o;
}

// ---------------------------------------------------------------------------
// Output projection, bf16 MFMA
// ---------------------------------------------------------------------------
__global__ __launch_bounds__(256) void out_mfma(const ushort* __restrict__ att16,
        const ushort* __restrict__ wo16, const float* __restrict__ bias,
        float* __restrict__ out) {
    __shared__ __align__(16) ushort Wls[4 * 520];
    __shared__ __align__(16) ushort Als[4 * 520];
    const int b = blockIdx.z;
    const int o0 = blockIdx.y * 64;
    const int n0 = blockIdx.x * 64;
    const int t = threadIdx.x;
    const int l = t & 63, w = t >> 6;
    const int q15 = l & 15, g = l >> 4;
    f32x4 acc[4];
#pragma unroll
    for (int nn = 0; nn < 4; ++nn) acc[nn] = (f32x4){0.f, 0.f, 0.f, 0.f};
    const int srow = t >> 2, sg = t & 3;
    const ushort* wsrc = wo16 + (size_t)(o0 + srow) * INNER + sg * 8;
    const ushort* asrc = att16 + ((size_t)b * N_SEQ + n0 + srow) * INNER + sg * 8;
    uint4 wreg = *(const uint4*)wsrc;
    uint4 areg = *(const uint4*)asrc;
    for (int k0 = 0; k0 < INNER; k0 += 32) {
        __builtin_amdgcn_s_barrier();
        __builtin_amdgcn_sched_barrier(0);
        *(uint4*)(Wls + sg * 520 + srow * 8) = wreg;
        *(uint4*)(Als + sg * 520 + srow * 8) = areg;
        if (k0 + 32 < INNER) {
            wreg = *(const uint4*)(wsrc + k0 + 32);
            areg = *(const uint4*)(asrc + k0 + 32);
        }
        asm volatile("s_waitcnt lgkmcnt(0)" ::: "memory");
        __builtin_amdgcn_s_barrier();
        __builtin_amdgcn_sched_barrier(0);
        bf16x8 af = *(const bf16x8*)(Wls + g * 520 + (16 * w + q15) * 8);
        __builtin_amdgcn_s_setprio(1);
#pragma unroll
        for (int nn = 0; nn < 4; ++nn) {
            bf16x8 bfr = *(const bf16x8*)(Als + g * 520 + (16 * nn + q15) * 8);
            acc[nn] = __builtin_amdgcn_mfma_f32_16x16x32_bf16(af, bfr, acc[nn], 0, 0, 0);
        }
        __builtin_amdgcn_s_setprio(0);
    }
    const int obase = o0 + 16 * w + 4 * g;
    float4 bi = *(const float4*)(bias + obase);
    float* ob = out + ((size_t)b * DIMC + obase) * N_SEQ;
#pragma unroll
    for (int nn = 0; nn < 4; ++nn) {
        const int n_ = n0 + 16 * nn + q15;
        ob[0 * N_SEQ + n_] = acc[nn][0] + bi.x;
        ob[1 * N_SEQ + n_] = acc[nn][1] + bi.y;
        ob[2 * N_SEQ + n_] = acc[nn][2] + bi.z;
        ob[3 * N_SEQ + n_] = acc[nn][3] + bi.w;
    }
}

extern "C" void kernel_launch(void* const* d_in, const int* in_sizes, int n_in,
                              void* d_out, int out_size, void* d_ws, size_t ws_size,
                              hipStream_t stream) {
    const float* x = (const float*)d_in[0];
    const float* w_qkv = (const float*)d_in[1];
    const float* w_out = (const float*)d_in[2];
    const float* b_out = (const float*)d_in[3];
    ushort* ws16 = (ushort*)d_ws;
    float* q2f = (float*)((char*)d_ws + (12 << 20));
    float* k2f = (float*)((char*)d_ws + (12 << 20) + (256 << 10));
    float* lpart = (float*)((char*)d_ws + (12 << 20) + (512 << 10));
    float* Opart = (float*)((char*)d_ws + (13 << 20));
    ushort* att16 = (ushort*)d_ws;                       // over dead Q region
    ushort* xt16 = (ushort*)((char*)d_ws + (21 << 20));
    ushort* wq16 = (ushort*)((char*)d_ws + (29 << 20));
    ushort* wo16 = (ushort*)((char*)d_ws + (30 << 20));
    float* out = (float*)d_out;

    xpose_cvt<<<dim3(32, 8, 4), 256, 0, stream>>>(x, xt16);
    wcvt2<<<dim3(512), 256, 0, stream>>>(w_qkv, w_out, wq16, wo16);
    qkv_mfma<<<dim3(32, 12, 4), 256, 0, stream>>>(xt16, wq16, ws16);
    sq_kernel<<<dim3(256, 2), 256, 0, stream>>>(ws16, q2f, k2f);
    attn_partial<<<dim3(2048), 256, 0, stream>>>(ws16, q2f, k2f, Opart, lpart);
    combine_norm<<<dim3(2048), 256, 0, stream>>>(Opart, lpart, att16);
    out_mfma<<<dim3(32, 8, 4), 256, 0, stream>>>(att16, wo16, b_out, out);
}